// Round 1
// baseline (2620.319 us; speedup 1.0000x reference)
//
#include <hip/hip_runtime.h>

// HMGRUV2: 2-layer masked GRU scan. B=256, T=256, L=2, IN=256, H=256 (f32 io).
// Round 5:
//  Theory: scan is L2-BW-bound on weight re-fetch (22.5 TB/s of ~30-34 TB/s
//  achievable; VALUBusy 34%, HBM 1.4%, MfmaUtil 0, bank-conflict 0).
//  Change: 2 batches per block (grid 128). Each weight uint4 is loaded once
//  and feeds fdot2 accumulators for BOTH batches. Union-of-masks dispatch:
//  E[matrix-streams/step/block-pair] = 2.375 vs 3.0 separate -> 0.79x L2
//  traffic, 2x math per load. Epilogue runs on tid<512 (one 256-thread group
//  per batch) so reduce latency does not grow.

#define BB 256
#define TT 256
#define HH 256
#define MAT_U32 98304   // u32 words per packed matrix (768*256/2)
#define MAT_U4  24576   // uint4 words per packed matrix
#define NBT 65536       // B*T
#define GI_STRIDE 768

typedef unsigned int u32;
typedef _Float16 f16;
typedef _Float16 f16x2 __attribute__((ext_vector_type(2)));
typedef _Float16 f16x4 __attribute__((ext_vector_type(4)));
typedef _Float16 f16x8 __attribute__((ext_vector_type(8)));
typedef float f32x4 __attribute__((ext_vector_type(4)));

#if defined(__has_builtin)
#  if __has_builtin(__builtin_amdgcn_fdot2)
#    define HAVE_FDOT2 1
#  endif
#endif

__device__ __forceinline__ float dot2(f16x2 a, f16x2 b, float c) {
#ifdef HAVE_FDOT2
    return __builtin_amdgcn_fdot2(a, b, c, false);
#else
    return c + (float)a.x * (float)b.x + (float)a.y * (float)b.y;
#endif
}

union U4 { uint4 u; f16x2 h[4]; f16x8 v; };

__device__ __forceinline__ float sigm(float x) { return 1.0f / (1.0f + __expf(-x)); }
__device__ __forceinline__ float tanhx(float x) { return 1.0f - 2.0f / (__expf(2.0f * x) + 1.0f); }

// ---- pack f32 weights -> f16 pairs (round-3 proven layout) ----
// u32 flat (per matrix m) = k8*3072 + g*1024 + j*4 + q ; k = k8*8 + q*2 (+1).
__global__ void pack_weights(const float* __restrict__ W_ih0,
                             const float* __restrict__ W_hh0,
                             const float* __restrict__ W_ih1,
                             const float* __restrict__ W_hh1,
                             u32* __restrict__ ws) {
    int tid = blockIdx.x * 256 + threadIdx.x;
    if (tid >= 6 * MAT_U32) return;
    int m  = tid / MAT_U32;
    int r  = tid % MAT_U32;
    int k8 = r / 3072;
    int r2 = r % 3072;
    int g  = r2 / 1024;
    int r3 = r2 % 1024;
    int jj = r3 >> 2;
    int q  = r3 & 3;
    int k  = k8 * 8 + q * 2;
    int c  = g * 256 + jj;
    float lo, hi;
    switch (m) {
        case 0: lo = W_ih0[c * 512 + k];       hi = W_ih0[c * 512 + k + 1];   break;
        case 1: lo = W_ih0[c * 512 + 256 + k]; hi = W_ih0[c * 512 + 257 + k]; break;
        case 2: lo = W_hh0[c * 256 + k];       hi = W_hh0[c * 256 + k + 1];   break;
        case 3: lo = W_ih1[c * 512 + k];       hi = W_ih1[c * 512 + k + 1];   break;
        case 4: lo = W_ih1[c * 512 + 256 + k]; hi = W_ih1[c * 512 + 257 + k]; break;
        default: lo = W_hh1[c * 256 + k];      hi = W_hh1[c * 256 + k + 1];   break;
    }
    union { f16x2 h; u32 u; } pk;
    pk.h.x = (f16)lo;
    pk.h.y = (f16)hi;
    ws[tid] = pk.u;
}

// ---- MFMA GEMM: gi[layer][bt][m] = sum_k W_ihLx[m][k] * x[bt][k]  (f16) ----
__global__ __launch_bounds__(256, 2) void proj_gemm(
    const float* __restrict__ x0, const float* __restrict__ x1,
    const uint4* __restrict__ Wt, f16* __restrict__ gi) {
    const int nblk  = blockIdx.x & 1023;
    const int layer = blockIdx.x >> 10;
    const int bt0   = nblk * 64;
    const float4* __restrict__ X4 = (const float4*)(layer ? x1 : x0);
    const uint4*  __restrict__ W  = Wt + (layer ? 3 : 0) * MAT_U4;
    f16* __restrict__ giL = gi + (size_t)layer * NBT * GI_STRIDE;

    __shared__ __align__(16) f16 xs[64 * 264];  // 64 rows x 256 f16, +8 pad

    const int tid = threadIdx.x;
    for (int it = 0; it < 16; ++it) {
        int idx = it * 256 + tid;
        int r = idx >> 6, c4 = idx & 63;
        float4 v = X4[(size_t)(bt0 + r) * 64 + c4];
        union { f16x4 h; unsigned long long u; } pk;
        pk.h = (f16x4){(f16)v.x, (f16)v.y, (f16)v.z, (f16)v.w};
        *(unsigned long long*)((char*)xs + r * 528 + c4 * 8) = pk.u;
    }
    __syncthreads();

    const int wave = tid >> 6;
    const int lane = tid & 63;
    const int l16  = lane & 15;
    const int quad = lane >> 4;

    for (int i = 0; i < 12; ++i) {
        const int mt = i * 4 + wave;   // m-tile 0..47
        const int m0 = mt * 16;
        const int g  = m0 >> 8;
        const int j0 = m0 & 255;
        f16x8 afr[8];
#pragma unroll
        for (int kst = 0; kst < 8; ++kst) {
            U4 a;
            a.u = W[((kst * 4 + quad) * 3 + g) * 256 + (j0 + l16)];
            afr[kst] = a.v;
        }
#pragma unroll
        for (int nt = 0; nt < 4; ++nt) {
            const int n0 = nt * 16;
            f32x4 acc = {0.f, 0.f, 0.f, 0.f};
#pragma unroll
            for (int kst = 0; kst < 8; ++kst) {
                f16x8 bfr = *(const f16x8*)((const char*)xs +
                               (n0 + l16) * 528 + kst * 64 + quad * 16);
                acc = __builtin_amdgcn_mfma_f32_16x16x32_f16(afr[kst], bfr, acc, 0, 0, 0);
            }
            const int col = bt0 + n0 + l16;
            union { f16x4 h; unsigned long long u; } o;
            o.h = (f16x4){(f16)acc[0], (f16)acc[1], (f16)acc[2], (f16)acc[3]};
            *(unsigned long long*)(giL + (size_t)col * GI_STRIDE + m0 + quad * 4) = o.u;
        }
    }
}

// ---- split-K partial GEMV, single batch: 8 k8-groups for unit j's 3 gates ----
__device__ __forceinline__ void gemv3p(const uint4* __restrict__ W, int j, int ksb,
                                       const uint4* __restrict__ s4,
                                       float& pr, float& pz, float& pn) {
#pragma unroll 4
    for (int i = 0; i < 8; ++i) {
        const int k8 = ksb + i;
        U4 sv, wr, wz, wn;
        sv.u = s4[k8];
        wr.u = W[(k8 * 3 + 0) * 256 + j];
        wz.u = W[(k8 * 3 + 1) * 256 + j];
        wn.u = W[(k8 * 3 + 2) * 256 + j];
#pragma unroll
        for (int q = 0; q < 4; ++q) {
            pr = dot2(wr.h[q], sv.h[q], pr);
            pz = dot2(wz.h[q], sv.h[q], pz);
            pn = dot2(wn.h[q], sv.h[q], pn);
        }
    }
}

// ---- dual-batch variant: weights loaded ONCE, used for both state vectors ----
__device__ __forceinline__ void gemv3p2(const uint4* __restrict__ W, int j, int ksb,
                                        const uint4* __restrict__ sA,
                                        const uint4* __restrict__ sB,
                                        float& prA, float& pzA, float& pnA,
                                        float& prB, float& pzB, float& pnB) {
#pragma unroll 4
    for (int i = 0; i < 8; ++i) {
        const int k8 = ksb + i;
        U4 svA, svB, wr, wz, wn;
        svA.u = sA[k8];
        svB.u = sB[k8];
        wr.u = W[(k8 * 3 + 0) * 256 + j];
        wz.u = W[(k8 * 3 + 1) * 256 + j];
        wn.u = W[(k8 * 3 + 2) * 256 + j];
#pragma unroll
        for (int q = 0; q < 4; ++q) {
            prA = dot2(wr.h[q], svA.h[q], prA);
            pzA = dot2(wz.h[q], svA.h[q], pzA);
            pnA = dot2(wn.h[q], svA.h[q], pnA);
            prB = dot2(wr.h[q], svB.h[q], prB);
            pzB = dot2(wz.h[q], svB.h[q], pzB);
            pnB = dot2(wn.h[q], svB.h[q], pnB);
        }
    }
}

// block-uniform dispatch: share weight stream when both batches need it
__device__ __forceinline__ void gemv_sel(const uint4* __restrict__ W, int j, int ksb,
                                         const uint4* __restrict__ sA,
                                         const uint4* __restrict__ sB,
                                         int dA, int dB,
                                         float& prA, float& pzA, float& pnA,
                                         float& prB, float& pzB, float& pnB) {
    if (dA & dB)      gemv3p2(W, j, ksb, sA, sB, prA, pzA, pnA, prB, pzB, pnB);
    else if (dA)      gemv3p(W, j, ksb, sA, prA, pzA, pnA);
    else if (dB)      gemv3p(W, j, ksb, sB, prB, pzB, pnB);
}

template <bool PRECOMP>
__global__ __launch_bounds__(1024, 4) void hmgru_scan(
    const float* __restrict__ x0, const float* __restrict__ x1,
    const float* __restrict__ hx0, const float* __restrict__ hx1,
    const float* __restrict__ b_ih0, const float* __restrict__ b_hh0,
    const float* __restrict__ b_ih1, const float* __restrict__ b_hh1,
    const int* __restrict__ dx, const int* __restrict__ dxlz,
    const uint4* __restrict__ Wt, const f16* __restrict__ gi,
    float* __restrict__ out) {
    const int bA  = blockIdx.x * 2;       // batch pair (bA, bA+1)
    const int tid = threadIdx.x;
    const int j   = tid & 255;
    const int ks  = tid >> 8;
    const int ksb = ks * 8;
    const int u   = ks & 1;               // batch slot for epilogue (tid<512)
    const int bu  = bA + u;

    const uint4* W_ih0x = Wt + 0 * MAT_U4;
    const uint4* W_ih0h = Wt + 1 * MAT_U4;
    const uint4* W_hh0  = Wt + 2 * MAT_U4;
    const uint4* W_ih1x = Wt + 3 * MAT_U4;
    const uint4* W_ih1h = Wt + 4 * MAT_U4;
    const uint4* W_hh1  = Wt + 5 * MAT_U4;
    const f16* gi0 = gi;
    const f16* gi1 = gi + (size_t)NBT * GI_STRIDE;

    __shared__ __align__(16) f16 h0s[2][2][256], h1s[2][2][256];   // [batch][buf][j]
    __shared__ __align__(16) f16 x0sh[2][2][256], x1sh[2][2][256]; // fallback only
    __shared__ float rbuf[2 * 6 * 4 * 256];                        // [batch][c][ks][j] 48KB
    __shared__ int m0s[2][TT], mAs[2][TT], mBs[2][TT];

    // biases: fold r/z into sums; n-gate needs ih/hh parts separate
    const float sb0r = b_ih0[j] + b_hh0[j];
    const float sb0z = b_ih0[256 + j] + b_hh0[256 + j];
    const float bi0n = b_ih0[512 + j], bh0n = b_hh0[512 + j];
    const float sb1r = b_ih1[j] + b_hh1[j];
    const float sb1z = b_ih1[256 + j] + b_hh1[256 + j];
    const float bi1n = b_ih1[512 + j], bh1n = b_hh1[512 + j];

    // (b1=0, dd1=1): bias-only GRU constant.
    const float c1r = sigm(sb1r);
    const float c1z = sigm(sb1z);
    const float c1n = tanhx(bi1n + c1r * bh1n);
    const float c1v = (1.0f - c1z) * c1n;

    const float* x0bu = x0 + (size_t)bu * TT * 256;
    const float* x1bu = x1 + (size_t)bu * TT * 256;
    float* out0u = out + (size_t)bu * TT * HH;
    float* out1u = out + (size_t)(BB + bu) * TT * HH;

    float h0reg = 0.f, h1reg = 0.f;
    if (tid < 512) {
        h0reg = hx0[bu * HH + j];
        h1reg = hx1[bu * HH + j];
        h0s[u][0][j] = (f16)h0reg;
        h1s[u][0][j] = (f16)h1reg;
        if (!PRECOMP) {
            x0sh[u][0][j] = (f16)x0bu[j];
            x1sh[u][0][j] = (f16)x1bu[j];
        }
        m0s[u][j] = dxlz[bu * TT + j];
        mAs[u][j] = dx[bu * 2 * TT + j];
        mBs[u][j] = dx[bu * 2 * TT + TT + j];
    }
    __syncthreads();

    int p = 0;
    for (int t = 0; t < TT; ++t) {
        const int b0A = m0s[0][t], b0B = m0s[1][t];
        const int b1A = mAs[0][t], b1B = mAs[1][t];
        const int dd0A = t ? mAs[0][t - 1] : 0, dd0B = t ? mAs[1][t - 1] : 0;
        const int dd1A = t ? mBs[0][t - 1] : 0, dd1B = t ? mBs[1][t - 1] : 0;
        // per-batch views for epilogue threads
        const int b0u  = u ? b0B : b0A;
        const int b1u  = u ? b1B : b1A;
        const int dd0u = u ? dd0B : dd0A;
        const int dd1u = u ? dd1B : dd1A;

        // fallback: prefetch x(t+1) into the other buffer
        if (!PRECOMP && tid < 512 && (t + 1) < TT) {
            x0sh[u][p ^ 1][j] = (f16)x0bu[(t + 1) * 256 + j];
            x1sh[u][p ^ 1][j] = (f16)x1bu[(t + 1) * 256 + j];
        }
        // precomp: prefetch gi rows (hidden behind GEMVs)
        float g0r = 0.f, g0z = 0.f, g0n = 0.f, g1r = 0.f, g1z = 0.f, g1n = 0.f;
        if (PRECOMP && tid < 512) {
            const int bt = bu * TT + t;
            if (b0u) {
                const f16* pg = gi0 + (size_t)bt * GI_STRIDE;
                g0r = (float)pg[j]; g0z = (float)pg[256 + j]; g0n = (float)pg[512 + j];
            }
            if (b1u) {
                const f16* pg = gi1 + (size_t)bt * GI_STRIDE;
                g1r = (float)pg[j]; g1z = (float)pg[256 + j]; g1n = (float)pg[512 + j];
            }
        }

        // ---------------- Layer 0 ----------------
        const int l0gA = b0A | dd0A, l0gB = b0B | dd0B;
        if (l0gA | l0gB) {
            float pirA = 0.f, pizA = 0.f, pinA = 0.f, phrA = 0.f, phzA = 0.f, phnA = 0.f;
            float pirB = 0.f, pizB = 0.f, pinB = 0.f, phrB = 0.f, phzB = 0.f, phnB = 0.f;
            if (!PRECOMP && (b0A | b0B))
                gemv_sel(W_ih0x, j, ksb, (const uint4*)x0sh[0][p], (const uint4*)x0sh[1][p],
                         b0A, b0B, pirA, pizA, pinA, pirB, pizB, pinB);
            if (dd0A | dd0B)
                gemv_sel(W_ih0h, j, ksb, (const uint4*)h1s[0][p], (const uint4*)h1s[1][p],
                         dd0A, dd0B, pirA, pizA, pinA, pirB, pizB, pinB);
            const int hA = b0A & (dd0A ^ 1), hB = b0B & (dd0B ^ 1);
            if (hA | hB)
                gemv_sel(W_hh0, j, ksb, (const uint4*)h0s[0][p], (const uint4*)h0s[1][p],
                         hA, hB, phrA, phzA, phnA, phrB, phzB, phnB);
            if (l0gA) {
                rbuf[(0 * 4 + ks) * 256 + j] = pirA;
                rbuf[(1 * 4 + ks) * 256 + j] = pizA;
                rbuf[(2 * 4 + ks) * 256 + j] = pinA;
                rbuf[(3 * 4 + ks) * 256 + j] = phrA;
                rbuf[(4 * 4 + ks) * 256 + j] = phzA;
                rbuf[(5 * 4 + ks) * 256 + j] = phnA;
            }
            if (l0gB) {
                rbuf[((6 + 0) * 4 + ks) * 256 + j] = pirB;
                rbuf[((6 + 1) * 4 + ks) * 256 + j] = pizB;
                rbuf[((6 + 2) * 4 + ks) * 256 + j] = pinB;
                rbuf[((6 + 3) * 4 + ks) * 256 + j] = phrB;
                rbuf[((6 + 4) * 4 + ks) * 256 + j] = phzB;
                rbuf[((6 + 5) * 4 + ks) * 256 + j] = phnB;
            }
            __syncthreads();  // B1: partials visible
        }
        if (tid < 512) {
            float h0n;
            if (!(b0u | dd0u)) {
                h0n = h0reg;  // pure carry
            } else {
                float air = g0r, aiz = g0z, ain = g0n;
                float ahr = 0.f, ahz = 0.f, ahn = 0.f;
                const int base = u * 24;
#pragma unroll
                for (int s = 0; s < 4; ++s) {
                    air += rbuf[(base + 0 * 4 + s) * 256 + j];
                    aiz += rbuf[(base + 1 * 4 + s) * 256 + j];
                    ain += rbuf[(base + 2 * 4 + s) * 256 + j];
                    ahr += rbuf[(base + 3 * 4 + s) * 256 + j];
                    ahz += rbuf[(base + 4 * 4 + s) * 256 + j];
                    ahn += rbuf[(base + 5 * 4 + s) * 256 + j];
                }
                const float h0cur = dd0u ? 0.0f : h0reg;
                const float r = sigm(air + ahr + sb0r);
                const float z = sigm(aiz + ahz + sb0z);
                const float n = tanhx(ain + bi0n + r * (ahn + bh0n));
                h0n = (1.0f - z) * n + z * h0cur;
            }
            out0u[t * HH + j] = h0n;
            h0s[u][p ^ 1][j] = (f16)h0n;
            h0reg = h0n;
        }
        __syncthreads();  // B2: new h0 visible, rbuf free

        // ---------------- Layer 1 ----------------
        if (b1A | b1B) {
            float pirA = 0.f, pizA = 0.f, pinA = 0.f, phrA = 0.f, phzA = 0.f, phnA = 0.f;
            float pirB = 0.f, pizB = 0.f, pinB = 0.f, phrB = 0.f, phzB = 0.f, phnB = 0.f;
            if (!PRECOMP)
                gemv_sel(W_ih1x, j, ksb, (const uint4*)x1sh[0][p], (const uint4*)x1sh[1][p],
                         b1A, b1B, pirA, pizA, pinA, pirB, pizB, pinB);
            gemv_sel(W_ih1h, j, ksb, (const uint4*)h0s[0][p ^ 1], (const uint4*)h0s[1][p ^ 1],
                     b1A, b1B, pirA, pizA, pinA, pirB, pizB, pinB);  // new h0
            const int hA = b1A & (dd1A ^ 1), hB = b1B & (dd1B ^ 1);
            if (hA | hB)
                gemv_sel(W_hh1, j, ksb, (const uint4*)h1s[0][p], (const uint4*)h1s[1][p],
                         hA, hB, phrA, phzA, phnA, phrB, phzB, phnB);
            if (b1A) {
                rbuf[(0 * 4 + ks) * 256 + j] = pirA;
                rbuf[(1 * 4 + ks) * 256 + j] = pizA;
                rbuf[(2 * 4 + ks) * 256 + j] = pinA;
                rbuf[(3 * 4 + ks) * 256 + j] = phrA;
                rbuf[(4 * 4 + ks) * 256 + j] = phzA;
                rbuf[(5 * 4 + ks) * 256 + j] = phnA;
            }
            if (b1B) {
                rbuf[((6 + 0) * 4 + ks) * 256 + j] = pirB;
                rbuf[((6 + 1) * 4 + ks) * 256 + j] = pizB;
                rbuf[((6 + 2) * 4 + ks) * 256 + j] = pinB;
                rbuf[((6 + 3) * 4 + ks) * 256 + j] = phrB;
                rbuf[((6 + 4) * 4 + ks) * 256 + j] = phzB;
                rbuf[((6 + 5) * 4 + ks) * 256 + j] = phnB;
            }
            __syncthreads();  // B3
        }
        if (tid < 512) {
            float h1n;
            if (!b1u) {
                h1n = dd1u ? c1v : h1reg;
            } else {
                float air = g1r, aiz = g1z, ain = g1n;
                float ahr = 0.f, ahz = 0.f, ahn = 0.f;
                const int base = u * 24;
#pragma unroll
                for (int s = 0; s < 4; ++s) {
                    air += rbuf[(base + 0 * 4 + s) * 256 + j];
                    aiz += rbuf[(base + 1 * 4 + s) * 256 + j];
                    ain += rbuf[(base + 2 * 4 + s) * 256 + j];
                    ahr += rbuf[(base + 3 * 4 + s) * 256 + j];
                    ahz += rbuf[(base + 4 * 4 + s) * 256 + j];
                    ahn += rbuf[(base + 5 * 4 + s) * 256 + j];
                }
                const float h1cur = dd1u ? 0.0f : h1reg;
                const float r = sigm(air + ahr + sb1r);
                const float z = sigm(aiz + ahz + sb1z);
                const float n = tanhx(ain + bi1n + r * (ahn + bh1n));
                h1n = (1.0f - z) * n + z * h1cur;
            }
            out1u[t * HH + j] = h1n;
            h1s[u][p ^ 1][j] = (f16)h1n;
            h1reg = h1n;
        }
        __syncthreads();  // B4: new h1 visible, rbuf free
        p ^= 1;
    }
}

extern "C" void kernel_launch(void* const* d_in, const int* in_sizes, int n_in,
                              void* d_out, int out_size, void* d_ws, size_t ws_size,
                              hipStream_t stream) {
    const float* x0    = (const float*)d_in[0];
    const float* x1    = (const float*)d_in[1];
    const float* hx0   = (const float*)d_in[2];
    const float* hx1   = (const float*)d_in[3];
    const float* W_ih0 = (const float*)d_in[4];
    const float* W_hh0 = (const float*)d_in[5];
    const float* b_ih0 = (const float*)d_in[6];
    const float* b_hh0 = (const float*)d_in[7];
    const float* W_ih1 = (const float*)d_in[8];
    const float* W_hh1 = (const float*)d_in[9];
    const float* b_ih1 = (const float*)d_in[10];
    const float* b_hh1 = (const float*)d_in[11];
    const int* dx      = (const int*)d_in[12];
    const int* dxlz    = (const int*)d_in[13];
    float* out = (float*)d_out;

    const size_t sz_w  = (size_t)6 * MAT_U32 * sizeof(u32);         // 2.36 MB
    const size_t sz_gi = (size_t)2 * NBT * GI_STRIDE * sizeof(f16); // 201.3 MB
    const bool precomp = (d_ws != nullptr) && (ws_size >= sz_w + sz_gi);

    u32* ws = (u32*)d_ws;
    const int total = 6 * MAT_U32;
    pack_weights<<<(total + 255) / 256, 256, 0, stream>>>(W_ih0, W_hh0, W_ih1, W_hh1, ws);

    f16* gi = (f16*)((char*)d_ws + sz_w);
    if (precomp) {
        proj_gemm<<<2048, 256, 0, stream>>>(x0, x1, (const uint4*)ws, gi);
        hmgru_scan<true><<<BB / 2, 1024, 0, stream>>>(
            x0, x1, hx0, hx1, b_ih0, b_hh0, b_ih1, b_hh1, dx, dxlz,
            (const uint4*)ws, gi, out);
    } else {
        hmgru_scan<false><<<BB / 2, 1024, 0, stream>>>(
            x0, x1, hx0, hx1, b_ih0, b_hh0, b_ih1, b_hh1, dx, dxlz,
            (const uint4*)ws, gi, out);
    }
}